// Round 10
// baseline (5173.256 us; speedup 1.0000x reference)
//
#include <hip/hip_runtime.h>
#include <hip/hip_bf16.h>
#include <stdint.h>

#define HD   512   // hidden dim H
#define ID   128   // input dim I
#define NCLS 100   // num classes
#define TT   512   // sequence length T
#define BB   128   // batch B
#define NEMB 101   // NC + 1 embedding rows
#define NGRP 32    // independent batch groups
#define GWG  8     // workgroups per group (sync clique)
#define RPG  4     // batch rows per group
#define COLS 64    // hidden cols per WG (GWG*COLS == HD)
#define THR  1024  // threads per recurrence WG (16 waves, 4 waves/SIMD)
#define CPAD 520   // LDS C row stride (8-float pad: keeps 16B align, skews banks)

// workspace layout (bytes)
#define WS_FLAG 0
#define WS_BAR  1024                  // uint bars[NGRP*32] (128 B apart)
#define WS_G    16384                 // float G[101][2048]  (808 KB)
#define WS_C0   (1u * 1024 * 1024)    // float C0[128][512]  (256 KB)
#define WS_C1   (WS_C0 + 262144)      // float C1[128][512]  (256 KB)
#define WS_HFB  (WS_C1 + 262144)      // float Hfb[128][512] (256 KB)

using bf16 = __hip_bfloat16;

__device__ __forceinline__ float b2f(bf16 v) { return __bfloat162float(v); }
__device__ __forceinline__ float sigf(float x) { return 1.0f / (1.0f + expf(-x)); }

// coherent (IF-scope) C-state accessors: sc1 loads/stores bypass the
// non-coherent per-XCD L2 — no fences / cache-maintenance needed (proven r6-r8).
__device__ __forceinline__ float cld(const float* p) {
    return __hip_atomic_load(p, __ATOMIC_RELAXED, __HIP_MEMORY_SCOPE_AGENT);
}
__device__ __forceinline__ void cst(float* p, float v) {
    __hip_atomic_store(p, v, __ATOMIC_RELAXED, __HIP_MEMORY_SCOPE_AGENT);
}

template <bool BF>
__device__ __forceinline__ float ldv(const void* p, int i) {
    if constexpr (BF) return b2f(((const bf16*)p)[i]);
    else              return ((const float*)p)[i];
}

// ---------------------------------------------------------------------------
// Dtype sniffer + barrier zeroing. emb row 0 is exactly 0.0 by construction:
// bytes [256,512) are zero iff f32 (row 0) and nonzero iff bf16 (row 1).
// ---------------------------------------------------------------------------
__global__ void init_k(const uint32_t* __restrict__ emb_raw,
                       int* __restrict__ flag, unsigned int* __restrict__ bars) {
    const int t = threadIdx.x;
    if (t < NGRP * 32) bars[t] = 0u;
    if (t == 0) {
        uint32_t acc = 0;
        for (int i = 64; i < 128; ++i) acc |= emb_raw[i];
        *flag = (acc == 0u) ? 0 : 1;
    }
}

// ---------------------------------------------------------------------------
// G[c][j]: input-side gate pre-activations per class. j = q*512 + col,
// q in {0:f, 1:i, 2:o, 3:ctilde}; ctilde quarter pre-sigmoided.
// ---------------------------------------------------------------------------
template <bool BF>
__global__ void build_G(const int* __restrict__ flag,
                        const void* __restrict__ emb,
                        const void* __restrict__ Wfx, const void* __restrict__ Wix,
                        const void* __restrict__ Wox, const void* __restrict__ Wcx,
                        const void* __restrict__ bfv, const void* __restrict__ biv,
                        const void* __restrict__ bov, const void* __restrict__ bcv,
                        float* __restrict__ G) {
    if (*flag != (BF ? 1 : 0)) return;
    const int c   = blockIdx.x;
    const int j   = blockIdx.y * 256 + threadIdx.x;
    const int q   = j >> 9;
    const int col = j & 511;
    const void* W  = (q == 0) ? Wfx : (q == 1) ? Wix : (q == 2) ? Wox : Wcx;
    const void* bv = (q == 0) ? bfv : (q == 1) ? biv : (q == 2) ? bov : bcv;
    float acc = ldv<BF>(bv, col);
    for (int i = 0; i < ID; ++i)
        acc += ldv<BF>(emb, c * ID + i) * ldv<BF>(W, i * HD + col);
    if (q == 3) acc = sigf(acc);
    G[c * 2048 + j] = acc;
}

// ---------------------------------------------------------------------------
// Group-local barrier, fence-free (sc1 data path + relaxed agent atomics).
// The leading __syncthreads drains each wave's sc1 C stores (vmcnt(0))
// before the leader's arrive. Proven in rounds 6-8.
// ---------------------------------------------------------------------------
__device__ __forceinline__ void gbarrier(unsigned int* cnt, unsigned int* iter) {
    __syncthreads();
    if (threadIdx.x == 0) {
        __hip_atomic_fetch_add(cnt, 1u, __ATOMIC_RELAXED, __HIP_MEMORY_SCOPE_AGENT);
        const unsigned int tgt = (*iter + 1u) * GWG;
        while (__hip_atomic_load(cnt, __ATOMIC_RELAXED, __HIP_MEMORY_SCOPE_AGENT) < tgt)
            __builtin_amdgcn_s_sleep(1);
    }
    ++*iter;
    __syncthreads();
}

// ---------------------------------------------------------------------------
// Batch-split recurrence, 1024 threads (16 waves -> 4 waves/SIMD -> hard
// 128-VGPR cap). Wave w: gate g=w>>3 (0:f, 1:i), h'-segment seg=w&7 (64
// wide); lane l owns column h0+l. Only 64 pinned weights/thread, so
// 64 + ~55 working regs fits under 128 — NO spill (rounds 7/8 spilled a
// 128-float array; FETCH showed the 8 MB/step scratch reload that was the
// entire bottleneck). Per step:
//   stage C(t) into LDS (2 coalesced sc1 loads/thread) -> sync
//   dot: 16x float4 LDS broadcast x 4 rows = 256 FMA/thread
//   partials to LDS (stride-5, conflict-free) -> sync
//   256 update threads: sum 8 partials/gate, apply gates (own C in Creg),
//   sc1-store 64-col slice -> group barrier.
// o-gate once at the end (h is dead state mid-sequence).
// ---------------------------------------------------------------------------
template <bool BF>
__global__ __launch_bounds__(THR, 1) void recur_bs(
    const int* __restrict__ flag, const int* __restrict__ x,
    const float* __restrict__ G,
    const void* __restrict__ Wfc, const void* __restrict__ Wic,
    const void* __restrict__ Woc,
    float* __restrict__ C0, float* __restrict__ C1,
    float* __restrict__ Hfb, unsigned int* __restrict__ bars)
{
    if (*flag != (BF ? 1 : 0)) return;

    __shared__ __align__(16) float Cs[RPG * CPAD];   // 8.3 KB
    __shared__ float part[16 * 64 * 5];              // 20.5 KB
    __shared__ int   idx[RPG * TT];                  // 8 KB
    __shared__ int   lz[RPG];

    const int blk  = blockIdx.x;
    const int grp  = (blk & 7) * 4 + ((blk >> 3) >> 3);  // 0..31
    const int rank = (blk >> 3) & 7;                     // 0..7
    const int r0   = grp * RPG;
    const int h0   = rank * COLS;
    const int tid  = threadIdx.x;
    const int w    = tid >> 6;            // wave 0..15
    const int l    = tid & 63;            // lane = col within WG
    unsigned int* bar = bars + grp * 32;  // 128 B apart

    // ---- stage x rows (2048 entries, 2/thread), find group start step ----
    {
        int e = tid;
        idx[(e >> 9) * TT + (e & 511)] = x[(r0 + (e >> 9)) * TT + (e & 511)];
        e = tid + 1024;
        idx[(e >> 9) * TT + (e & 511)] = x[(r0 + (e >> 9)) * TT + (e & 511)];
    }
    if (tid < RPG) lz[tid] = -1;
    __syncthreads();
    if (tid < TT)
        for (int r = 0; r < RPG; ++r)
            if (idx[r * TT + tid] == 0) atomicMax(&lz[r], tid);
    __syncthreads();
    const int t0 = min(min(lz[0], lz[1]), min(lz[2], lz[3])) + 1;

    // ---- 64 pinned register weights: one gate, own col, own h' segment ----
    const int g = w >> 3, seg = w & 7;
    float wreg[64];
    {
        const void* Ws = g ? Wic : Wfc;
        #pragma unroll
        for (int k = 0; k < 64; ++k)
            wreg[k] = ldv<BF>(Ws, (seg * 64 + k) * HD + h0 + l);
        #pragma unroll
        for (int k = 0; k < 64; ++k)
            asm volatile("" : "+v"(wreg[k]));
    }

    // ---- zero own C slices in both buffers (coherent stores) ----
    if (tid < COLS * RPG) {
        const int col = tid & 63, r = tid >> 6;
        cst(&C0[(r0 + r) * HD + h0 + col], 0.0f);
        cst(&C1[(r0 + r) * HD + h0 + col], 0.0f);
    }
    unsigned int bi = 0;
    gbarrier(bar, &bi);                   // zeros visible group-wide

    float Creg = 0.0f;                    // update threads' own C element
    const int erow = tid >> 9, ehp = tid & 511;

    for (int t = t0; t < TT; ++t) {
        const float* cur = (t & 1) ? C1 : C0;
        float*       nxt = (t & 1) ? C0 : C1;

        // ---- stage C(t) into LDS: rows erow and erow+2 at h'=ehp ----
        {
            const float v0 = cld(cur + (r0 + erow) * HD + ehp);
            const float v1 = cld(cur + (r0 + erow + 2) * HD + ehp);
            Cs[erow * CPAD + ehp]       = v0;
            Cs[(erow + 2) * CPAD + ehp] = v1;
        }
        __syncthreads();

        // ---- own-col dot over 64 h' (wave-uniform LDS broadcast) ----
        float a0 = 0.f, a1 = 0.f, a2 = 0.f, a3 = 0.f;
        {
            const float4* b0 = reinterpret_cast<const float4*>(Cs + 0 * CPAD + seg * 64);
            const float4* b1 = reinterpret_cast<const float4*>(Cs + 1 * CPAD + seg * 64);
            const float4* b2 = reinterpret_cast<const float4*>(Cs + 2 * CPAD + seg * 64);
            const float4* b3 = reinterpret_cast<const float4*>(Cs + 3 * CPAD + seg * 64);
            #pragma unroll
            for (int j = 0; j < 16; ++j) {
                const float4 c0 = b0[j], c1 = b1[j], c2 = b2[j], c3 = b3[j];
                const float w0 = wreg[4*j],   w1 = wreg[4*j+1];
                const float w2 = wreg[4*j+2], w3 = wreg[4*j+3];
                a0 += w0*c0.x + w1*c0.y + w2*c0.z + w3*c0.w;
                a1 += w0*c1.x + w1*c1.y + w2*c1.z + w3*c1.w;
                a2 += w0*c2.x + w1*c2.y + w2*c2.z + w3*c2.w;
                a3 += w0*c3.x + w1*c3.y + w2*c3.z + w3*c3.w;
            }
        }
        {   // part[(w*64+l)*5 + r]: stride-5 scalar slots, conflict-free
            float* pp = part + (w * 64 + l) * 5;
            pp[0] = a0; pp[1] = a1; pp[2] = a2; pp[3] = a3;
        }
        __syncthreads();

        // ---- update: thread t<256 owns (col = t&63, row = t>>6) ----
        if (tid < COLS * RPG) {
            const int col = tid & 63, r = tid >> 6;
            float df = 0.f, di = 0.f;
            #pragma unroll
            for (int s2 = 0; s2 < 8; ++s2) {
                df += part[( s2      * 64 + col) * 5 + r];
                di += part[((8 + s2) * 64 + col) * 5 + r];
            }
            const int cl = idx[r * TT + t];
            const float* Gr = G + cl * 2048;
            float Cn = Gr[1536 + h0 + col] * sigf(Gr[512 + h0 + col] + di)
                     + Creg * sigf(Gr[h0 + col] + df);
            Cn = (cl > 0) ? Cn : 0.0f;
            Creg = Cn;
            cst(&nxt[(r0 + r) * HD + h0 + col], Cn);
        }
        gbarrier(bar, &bi);
    }

    // ---- o-gate + h once (h is dead mid-sequence; TT even -> final C in C0)
    {
        const float v0 = cld(C0 + (r0 + erow) * HD + ehp);
        const float v1 = cld(C0 + (r0 + erow + 2) * HD + ehp);
        Cs[erow * CPAD + ehp]       = v0;
        Cs[(erow + 2) * CPAD + ehp] = v1;
        __syncthreads();

        float ao0 = 0.f, ao1 = 0.f, ao2 = 0.f, ao3 = 0.f;
        #pragma unroll 8
        for (int k = 0; k < 32; ++k) {
            const int hp = w * 32 + k;               // 16 waves x 32 h'
            const float wo = ldv<BF>(Woc, hp * HD + h0 + l);
            ao0 += wo * Cs[0 * CPAD + hp];
            ao1 += wo * Cs[1 * CPAD + hp];
            ao2 += wo * Cs[2 * CPAD + hp];
            ao3 += wo * Cs[3 * CPAD + hp];
        }
        float* pp = part + (w * 64 + l) * 5;
        pp[0] = ao0; pp[1] = ao1; pp[2] = ao2; pp[3] = ao3;
        __syncthreads();
        if (tid < COLS * RPG) {
            const int col = tid & 63, r = tid >> 6;
            float s = 0.f;
            #pragma unroll
            for (int ww = 0; ww < 16; ++ww) s += part[(ww * 64 + col) * 5 + r];
            const int cl = idx[r * TT + TT - 1];
            const float o = sigf(G[cl * 2048 + 1024 + h0 + col] + s);
            Hfb[(r0 + r) * HD + h0 + col] = tanhf(Creg) * o;
        }
    }
}

// ---------------------------------------------------------------------------
// Projection + log_softmax, one WG per batch row.
// ---------------------------------------------------------------------------
template <bool BF>
__global__ __launch_bounds__(128) void proj(
    const int* __restrict__ flag, const float* __restrict__ Hfb,
    const void* __restrict__ Wph, const void* __restrict__ bp,
    void* __restrict__ out)
{
    if (*flag != (BF ? 1 : 0)) return;
    __shared__ __align__(16) float hv[HD];
    __shared__ float p_s[NCLS];
    __shared__ float lse_s;
    const int b   = blockIdx.x;
    const int tid = threadIdx.x;

    reinterpret_cast<float4*>(hv)[tid] =
        reinterpret_cast<const float4*>(Hfb + b * HD)[tid];
    __syncthreads();

    if (tid < NCLS) {
        float p = ldv<BF>(bp, tid);
        for (int h = 0; h < HD; ++h)
            p += hv[h] * ldv<BF>(Wph, h * NCLS + tid);
        p_s[tid] = p;
    }
    __syncthreads();
    if (tid == 0) {
        float m = -1e30f;
        for (int n = 0; n < NCLS; ++n) m = fmaxf(m, p_s[n]);
        float sum = 0.0f;
        for (int n = 0; n < NCLS; ++n) sum += expf(p_s[n] - m);
        lse_s = m + logf(sum);
    }
    __syncthreads();
    if (tid < NCLS) {
        const float v = p_s[tid] - lse_s;
        if constexpr (BF) ((bf16*)out)[b * NCLS + tid] = __float2bfloat16(v);
        else              ((float*)out)[b * NCLS + tid] = v;
    }
}

// ---------------------------------------------------------------------------
extern "C" void kernel_launch(void* const* d_in, const int* in_sizes, int n_in,
                              void* d_out, int out_size, void* d_ws, size_t ws_size,
                              hipStream_t stream) {
    const int*  x   = (const int*)d_in[0];
    const void* emb = d_in[1];
    const void* Wfx = d_in[2];
    const void* Wfc = d_in[3];
    const void* bfv = d_in[4];
    const void* Wix = d_in[5];
    const void* Wic = d_in[6];
    const void* biv = d_in[7];
    const void* Wox = d_in[8];
    const void* Woc = d_in[9];
    const void* bov = d_in[10];
    const void* Wcx = d_in[11];
    const void* bcv = d_in[12];
    const void* Wph = d_in[13];
    const void* bp  = d_in[14];

    int*          flag = (int*)((char*)d_ws + WS_FLAG);
    unsigned int* bars = (unsigned int*)((char*)d_ws + WS_BAR);
    float*        G    = (float*)((char*)d_ws + WS_G);
    float*        C0   = (float*)((char*)d_ws + WS_C0);
    float*        C1   = (float*)((char*)d_ws + WS_C1);
    float*        Hfb  = (float*)((char*)d_ws + WS_HFB);

    init_k<<<1, 1024, 0, stream>>>((const uint32_t*)emb, flag, bars);

    build_G<false><<<dim3(NEMB, 8), 256, 0, stream>>>(flag, emb, Wfx, Wix, Wox, Wcx,
                                                      bfv, biv, bov, bcv, G);
    build_G<true ><<<dim3(NEMB, 8), 256, 0, stream>>>(flag, emb, Wfx, Wix, Wox, Wcx,
                                                      bfv, biv, bov, bcv, G);

    {
        void* args[] = {(void*)&flag, (void*)&x, (void*)&G,
                        (void*)&Wfc, (void*)&Wic, (void*)&Woc,
                        (void*)&C0, (void*)&C1, (void*)&Hfb, (void*)&bars};
        hipLaunchCooperativeKernel((const void*)recur_bs<false>, dim3(NGRP * GWG), dim3(THR),
                                   args, 0, stream);
        hipLaunchCooperativeKernel((const void*)recur_bs<true>, dim3(NGRP * GWG), dim3(THR),
                                   args, 0, stream);
    }

    proj<false><<<BB, 128, 0, stream>>>(flag, Hfb, Wph, bp, d_out);
    proj<true ><<<BB, 128, 0, stream>>>(flag, Hfb, Wph, bp, d_out);
}

// Round 11
// 2599.703 us; speedup vs baseline: 1.9899x; 1.9899x over previous
//
#include <hip/hip_runtime.h>
#include <hip/hip_bf16.h>
#include <stdint.h>

#define HD   512   // hidden dim H
#define ID   128   // input dim I
#define NCLS 100   // num classes
#define TT   512   // sequence length T
#define BB   128   // batch B
#define NEMB 101   // NC + 1 embedding rows
#define NGRP 16    // independent batch groups
#define GWG  16    // workgroups per group (sync clique)
#define RPG  8     // batch rows per group
#define COLS 32    // hidden cols per WG (GWG*COLS == HD)
#define THR  1024  // threads per recurrence WG (16 waves, 4 waves/SIMD)
#define CPAD 520   // LDS C row stride (mult of 4 -> float4-aligned; skews banks)

// workspace layout (bytes)
#define WS_FLAG 0
#define WS_BAR  1024                  // uint bars[NGRP*32] (128 B apart)
#define WS_G    16384                 // float G[101][2048]  (808 KB)
#define WS_C0   (1u * 1024 * 1024)    // float C0[128][512]  (256 KB)
#define WS_C1   (WS_C0 + 262144)      // float C1[128][512]  (256 KB)
#define WS_HFB  (WS_C1 + 262144)      // float Hfb[128][512] (256 KB)

using bf16 = __hip_bfloat16;

__device__ __forceinline__ float b2f(bf16 v) { return __bfloat162float(v); }
__device__ __forceinline__ float sigf(float x) { return 1.0f / (1.0f + expf(-x)); }

// coherent (IF-scope) C-state accessors: sc1 loads/stores bypass the
// non-coherent per-XCD L2 — no fences / cache-maintenance needed (proven r6-r10).
__device__ __forceinline__ float cld(const float* p) {
    return __hip_atomic_load(p, __ATOMIC_RELAXED, __HIP_MEMORY_SCOPE_AGENT);
}
__device__ __forceinline__ void cst(float* p, float v) {
    __hip_atomic_store(p, v, __ATOMIC_RELAXED, __HIP_MEMORY_SCOPE_AGENT);
}

template <bool BF>
__device__ __forceinline__ float ldv(const void* p, int i) {
    if constexpr (BF) return b2f(((const bf16*)p)[i]);
    else              return ((const float*)p)[i];
}

// ---------------------------------------------------------------------------
// Dtype sniffer + barrier zeroing. emb row 0 is exactly 0.0 by construction:
// bytes [256,512) are zero iff f32 (row 0) and nonzero iff bf16 (row 1).
// ---------------------------------------------------------------------------
__global__ void init_k(const uint32_t* __restrict__ emb_raw,
                       int* __restrict__ flag, unsigned int* __restrict__ bars) {
    const int t = threadIdx.x;
    bars[t] = 0u;                      // 1024 slots (>= NGRP*32)
    if (t == 0) {
        uint32_t acc = 0;
        for (int i = 64; i < 128; ++i) acc |= emb_raw[i];
        *flag = (acc == 0u) ? 0 : 1;
    }
}

// ---------------------------------------------------------------------------
// G[c][j]: input-side gate pre-activations per class. j = q*512 + col,
// q in {0:f, 1:i, 2:o, 3:ctilde}; ctilde quarter pre-sigmoided.
// ---------------------------------------------------------------------------
template <bool BF>
__global__ void build_G(const int* __restrict__ flag,
                        const void* __restrict__ emb,
                        const void* __restrict__ Wfx, const void* __restrict__ Wix,
                        const void* __restrict__ Wox, const void* __restrict__ Wcx,
                        const void* __restrict__ bfv, const void* __restrict__ biv,
                        const void* __restrict__ bov, const void* __restrict__ bcv,
                        float* __restrict__ G) {
    if (*flag != (BF ? 1 : 0)) return;
    const int c   = blockIdx.x;
    const int j   = blockIdx.y * 256 + threadIdx.x;
    const int q   = j >> 9;
    const int col = j & 511;
    const void* W  = (q == 0) ? Wfx : (q == 1) ? Wix : (q == 2) ? Wox : Wcx;
    const void* bv = (q == 0) ? bfv : (q == 1) ? biv : (q == 2) ? bov : bcv;
    float acc = ldv<BF>(bv, col);
    for (int i = 0; i < ID; ++i)
        acc += ldv<BF>(emb, c * ID + i) * ldv<BF>(W, i * HD + col);
    if (q == 3) acc = sigf(acc);
    G[c * 2048 + j] = acc;
}

// ---------------------------------------------------------------------------
// Group-local barrier, fence-free (sc1 data path + relaxed agent atomics).
// The leading __syncthreads drains each wave's sc1 C stores (vmcnt(0))
// before the leader's arrive. Proven in rounds 6-10.
// ---------------------------------------------------------------------------
__device__ __forceinline__ void gbarrier(unsigned int* cnt, unsigned int* iter) {
    __syncthreads();
    if (threadIdx.x == 0) {
        __hip_atomic_fetch_add(cnt, 1u, __ATOMIC_RELAXED, __HIP_MEMORY_SCOPE_AGENT);
        const unsigned int tgt = (*iter + 1u) * GWG;
        while (__hip_atomic_load(cnt, __ATOMIC_RELAXED, __HIP_MEMORY_SCOPE_AGENT) < tgt)
            __builtin_amdgcn_s_sleep(1);
    }
    ++*iter;
    __syncthreads();
}

// ---------------------------------------------------------------------------
// Batch-split recurrence, 16 groups x 16 WGs x 32 cols. Thread t:
//   col = t&31 (own column h0+col), gc = t>>5: gate = gc&1 (0:f, 1:i),
//   chunk = gc>>1 (16 chunks x 32 h'). Only 32 pinned weights/thread:
//   32 + ~50 working regs << 128 hard cap at 4 waves/SIMD -> NO SPILL
//   (r7/r8/r10 all spilled larger arrays; FETCH showed 8 MB/step reload).
// Wave w holds gc = {2w, 2w+1} with identical chunk=w -> the dot's LDS C
// reads are wave-uniform float4 broadcasts (conflict-free).
// Per step: stage C(t) for 8 rows into LDS (4 sc1 loads/thread) -> dot
// (256 FMA/thread) -> stride-9 partials -> 256 update threads sum 16 chunks
// per gate, apply gates (own C in Creg), sc1-store -> group barrier.
// ---------------------------------------------------------------------------
template <bool BF>
__global__ __launch_bounds__(THR, 1) void recur_bs(
    const int* __restrict__ flag, const int* __restrict__ x,
    const float* __restrict__ G,
    const void* __restrict__ Wfc, const void* __restrict__ Wic,
    const void* __restrict__ Woc,
    float* __restrict__ C0, float* __restrict__ C1,
    float* __restrict__ Hfb, unsigned int* __restrict__ bars)
{
    if (*flag != (BF ? 1 : 0)) return;

    __shared__ __align__(16) float Cs[RPG * CPAD];   // 16.6 KB
    __shared__ float part[THR * 9];                  // 36.9 KB, stride 9
    __shared__ int   idx[RPG * TT];                  // 16 KB
    __shared__ int   lz[RPG];

    const int blk  = blockIdx.x;
    const int grp  = blk >> 4;            // 0..15
    const int rank = blk & 15;            // 0..15
    const int r0   = grp * RPG;
    const int h0   = rank * COLS;
    const int tid  = threadIdx.x;
    const int col  = tid & 31;
    const int gc   = tid >> 5;            // 0..31
    const int gate = gc & 1;
    const int chunk = gc >> 1;            // 0..15 (32 h' each)
    unsigned int* bar = bars + grp * 32;  // 128 B apart

    // ---- stage x rows (4096 ints, flat-contiguous), find group start ----
    #pragma unroll
    for (int k = 0; k < 4; ++k)
        idx[tid + 1024 * k] = x[r0 * TT + tid + 1024 * k];
    if (tid < RPG) lz[tid] = -1;
    __syncthreads();
    if (tid < TT)
        #pragma unroll
        for (int r = 0; r < RPG; ++r)
            if (idx[r * TT + tid] == 0) atomicMax(&lz[r], tid);
    __syncthreads();
    int t0 = TT;
    #pragma unroll
    for (int r = 0; r < RPG; ++r) t0 = min(t0, lz[r] + 1);

    // ---- 32 pinned register weights: own gate, own col, own h' chunk ----
    float wreg[32];
    {
        const void* Ws = gate ? Wic : Wfc;
        #pragma unroll
        for (int k = 0; k < 32; ++k)
            wreg[k] = ldv<BF>(Ws, (chunk * 32 + k) * HD + h0 + col);
        #pragma unroll
        for (int k = 0; k < 32; ++k)
            asm volatile("" : "+v"(wreg[k]));
    }

    // ---- zero own C slices in both buffers (coherent stores) ----
    if (tid < COLS * RPG) {
        const int c = tid & 31, r = tid >> 5;
        cst(&C0[(r0 + r) * HD + h0 + c], 0.0f);
        cst(&C1[(r0 + r) * HD + h0 + c], 0.0f);
    }
    unsigned int bi = 0;
    gbarrier(bar, &bi);                   // zeros visible group-wide

    float Creg = 0.0f;                    // update threads' own C element
    const int erow = tid >> 7;            // stage: row 0..7
    const int eh4  = (tid & 127) * 4;     // stage: h' base (4 consecutive)

    for (int t = t0; t < TT; ++t) {
        const float* cur = (t & 1) ? C1 : C0;
        float*       nxt = (t & 1) ? C0 : C1;

        // ---- stage C(t): 4 consecutive floats of row erow at h'=eh4 ----
        {
            const float* cb = cur + (r0 + erow) * HD + eh4;
            const float v0 = cld(cb);
            const float v1 = cld(cb + 1);
            const float v2 = cld(cb + 2);
            const float v3 = cld(cb + 3);
            float* cs = Cs + erow * CPAD + eh4;
            cs[0] = v0; cs[1] = v1; cs[2] = v2; cs[3] = v3;
        }
        __syncthreads();

        // ---- own-col dot over 32 h' (wave-uniform LDS broadcast) ----
        float acc[RPG];
        #pragma unroll
        for (int r = 0; r < RPG; ++r) acc[r] = 0.0f;
        {
            const int cb4 = chunk * 8;    // float4 index of chunk base
            #pragma unroll
            for (int j = 0; j < 8; ++j) {
                const float w0 = wreg[4*j],   w1 = wreg[4*j+1];
                const float w2 = wreg[4*j+2], w3 = wreg[4*j+3];
                #pragma unroll
                for (int r = 0; r < RPG; ++r) {
                    const float4 cv = reinterpret_cast<const float4*>(
                        Cs + r * CPAD)[cb4 + j];
                    acc[r] += w0*cv.x + w1*cv.y + w2*cv.z + w3*cv.w;
                }
            }
        }
        {
            float* pp = part + tid * 9;
            #pragma unroll
            for (int r = 0; r < RPG; ++r) pp[r] = acc[r];
        }
        __syncthreads();

        // ---- update: thread t<256 owns (col = t&31, row = t>>5) ----
        if (tid < COLS * RPG) {
            const int c = tid & 31, r = tid >> 5;
            float df = 0.f, di = 0.f;
            #pragma unroll
            for (int ch = 0; ch < 16; ++ch) {
                df += part[((ch * 64)      + c) * 9 + r];
                di += part[((ch * 64) + 32 + c) * 9 + r];
            }
            const int cl = idx[r * TT + t];
            const float* Gr = G + cl * 2048;
            float Cn = Gr[1536 + h0 + c] * sigf(Gr[512 + h0 + c] + di)
                     + Creg * sigf(Gr[h0 + c] + df);
            Cn = (cl > 0) ? Cn : 0.0f;
            Creg = Cn;
            cst(&nxt[(r0 + r) * HD + h0 + c], Cn);
        }
        gbarrier(bar, &bi);
    }

    // ---- o-gate + h once (h is dead mid-sequence; TT even -> final C in C0)
    {
        const float* cb = C0 + (r0 + erow) * HD + eh4;
        const float v0 = cld(cb);
        const float v1 = cld(cb + 1);
        const float v2 = cld(cb + 2);
        const float v3 = cld(cb + 3);
        float* cs = Cs + erow * CPAD + eh4;
        cs[0] = v0; cs[1] = v1; cs[2] = v2; cs[3] = v3;
        __syncthreads();

        // gc (0..31) = o-chunk of 16 h'
        float ao[RPG];
        #pragma unroll
        for (int r = 0; r < RPG; ++r) ao[r] = 0.0f;
        #pragma unroll 4
        for (int k = 0; k < 16; ++k) {
            const int hp = gc * 16 + k;
            const float wo = ldv<BF>(Woc, hp * HD + h0 + col);
            #pragma unroll
            for (int r = 0; r < RPG; ++r)
                ao[r] += wo * Cs[r * CPAD + hp];
        }
        float* pp = part + tid * 9;
        #pragma unroll
        for (int r = 0; r < RPG; ++r) pp[r] = ao[r];
        __syncthreads();
        if (tid < COLS * RPG) {
            const int c = tid & 31, r = tid >> 5;
            float s = 0.f;
            #pragma unroll
            for (int oc = 0; oc < 32; ++oc)
                s += part[(oc * 32 + c) * 9 + r];
            const int cl = idx[r * TT + TT - 1];
            const float o = sigf(G[cl * 2048 + 1024 + h0 + c] + s);
            Hfb[(r0 + r) * HD + h0 + c] = tanhf(Creg) * o;
        }
    }
}

// ---------------------------------------------------------------------------
// Projection + log_softmax, one WG per batch row.
// ---------------------------------------------------------------------------
template <bool BF>
__global__ __launch_bounds__(128) void proj(
    const int* __restrict__ flag, const float* __restrict__ Hfb,
    const void* __restrict__ Wph, const void* __restrict__ bp,
    void* __restrict__ out)
{
    if (*flag != (BF ? 1 : 0)) return;
    __shared__ __align__(16) float hv[HD];
    __shared__ float p_s[NCLS];
    __shared__ float lse_s;
    const int b   = blockIdx.x;
    const int tid = threadIdx.x;

    reinterpret_cast<float4*>(hv)[tid] =
        reinterpret_cast<const float4*>(Hfb + b * HD)[tid];
    __syncthreads();

    if (tid < NCLS) {
        float p = ldv<BF>(bp, tid);
        for (int h = 0; h < HD; ++h)
            p += hv[h] * ldv<BF>(Wph, h * NCLS + tid);
        p_s[tid] = p;
    }
    __syncthreads();
    if (tid == 0) {
        float m = -1e30f;
        for (int n = 0; n < NCLS; ++n) m = fmaxf(m, p_s[n]);
        float sum = 0.0f;
        for (int n = 0; n < NCLS; ++n) sum += expf(p_s[n] - m);
        lse_s = m + logf(sum);
    }
    __syncthreads();
    if (tid < NCLS) {
        const float v = p_s[tid] - lse_s;
        if constexpr (BF) ((bf16*)out)[b * NCLS + tid] = __float2bfloat16(v);
        else              ((float*)out)[b * NCLS + tid] = v;
    }
}

// ---------------------------------------------------------------------------
extern "C" void kernel_launch(void* const* d_in, const int* in_sizes, int n_in,
                              void* d_out, int out_size, void* d_ws, size_t ws_size,
                              hipStream_t stream) {
    const int*  x   = (const int*)d_in[0];
    const void* emb = d_in[1];
    const void* Wfx = d_in[2];
    const void* Wfc = d_in[3];
    const void* bfv = d_in[4];
    const void* Wix = d_in[5];
    const void* Wic = d_in[6];
    const void* biv = d_in[7];
    const void* Wox = d_in[8];
    const void* Woc = d_in[9];
    const void* bov = d_in[10];
    const void* Wcx = d_in[11];
    const void* bcv = d_in[12];
    const void* Wph = d_in[13];
    const void* bp  = d_in[14];

    int*          flag = (int*)((char*)d_ws + WS_FLAG);
    unsigned int* bars = (unsigned int*)((char*)d_ws + WS_BAR);
    float*        G    = (float*)((char*)d_ws + WS_G);
    float*        C0   = (float*)((char*)d_ws + WS_C0);
    float*        C1   = (float*)((char*)d_ws + WS_C1);
    float*        Hfb  = (float*)((char*)d_ws + WS_HFB);

    init_k<<<1, 1024, 0, stream>>>((const uint32_t*)emb, flag, bars);

    build_G<false><<<dim3(NEMB, 8), 256, 0, stream>>>(flag, emb, Wfx, Wix, Wox, Wcx,
                                                      bfv, biv, bov, bcv, G);
    build_G<true ><<<dim3(NEMB, 8), 256, 0, stream>>>(flag, emb, Wfx, Wix, Wox, Wcx,
                                                      bfv, biv, bov, bcv, G);

    {
        void* args[] = {(void*)&flag, (void*)&x, (void*)&G,
                        (void*)&Wfc, (void*)&Wic, (void*)&Woc,
                        (void*)&C0, (void*)&C1, (void*)&Hfb, (void*)&bars};
        hipLaunchCooperativeKernel((const void*)recur_bs<false>, dim3(NGRP * GWG), dim3(THR),
                                   args, 0, stream);
        hipLaunchCooperativeKernel((const void*)recur_bs<true>, dim3(NGRP * GWG), dim3(THR),
                                   args, 0, stream);
    }

    proj<false><<<BB, 128, 0, stream>>>(flag, Hfb, Wph, bp, d_out);
    proj<true ><<<BB, 128, 0, stream>>>(flag, Hfb, Wph, bp, d_out);
}

// Round 12
// 2281.969 us; speedup vs baseline: 2.2670x; 1.1392x over previous
//
#include <hip/hip_runtime.h>
#include <hip/hip_bf16.h>
#include <stdint.h>

#define HD   512   // hidden dim H
#define ID   128   // input dim I
#define NCLS 100   // num classes
#define TT   512   // sequence length T
#define BB   128   // batch B
#define NEMB 101   // NC + 1 embedding rows
#define NGRP 16    // independent batch groups
#define GWG  16    // workgroups per group (sync clique)
#define RPG  8     // batch rows per group
#define COLS 32    // hidden cols per WG (GWG*COLS == HD)
#define THR  1024  // threads per recurrence WG (16 waves, 4 waves/SIMD)
#define CPAD 520   // LDS C row stride (mult of 4 -> float4-aligned; skews banks)
#define PST  17    // partials stride (odd -> conflict-free)

// workspace layout (bytes)
#define WS_FLAG 0
#define WS_BAR  1024                  // uint bars[NGRP*32] (128 B apart)
#define WS_G    16384                 // float G[101][2048]  (808 KB)
#define WS_C0   (1u * 1024 * 1024)    // float C0[128][512]  (256 KB)
#define WS_C1   (WS_C0 + 262144)      // float C1[128][512]  (256 KB)
#define WS_HFB  (WS_C1 + 262144)      // float Hfb[128][512] (256 KB)

using bf16 = __hip_bfloat16;

__device__ __forceinline__ float b2f(bf16 v) { return __bfloat162float(v); }
__device__ __forceinline__ float sigf(float x) { return 1.0f / (1.0f + expf(-x)); }

// coherent (IF-scope) C-state accessors: sc1 loads/stores bypass the
// non-coherent per-XCD L2 — no fences / cache-maintenance needed (proven r6-r11).
__device__ __forceinline__ float cld(const float* p) {
    return __hip_atomic_load(p, __ATOMIC_RELAXED, __HIP_MEMORY_SCOPE_AGENT);
}
__device__ __forceinline__ void cst(float* p, float v) {
    __hip_atomic_store(p, v, __ATOMIC_RELAXED, __HIP_MEMORY_SCOPE_AGENT);
}

template <bool BF>
__device__ __forceinline__ float ldv(const void* p, int i) {
    if constexpr (BF) return b2f(((const bf16*)p)[i]);
    else              return ((const float*)p)[i];
}

// ---------------------------------------------------------------------------
// Dtype sniffer + barrier zeroing. emb row 0 is exactly 0.0 by construction:
// bytes [256,512) are zero iff f32 (row 0) and nonzero iff bf16 (row 1).
// ---------------------------------------------------------------------------
__global__ void init_k(const uint32_t* __restrict__ emb_raw,
                       int* __restrict__ flag, unsigned int* __restrict__ bars) {
    const int t = threadIdx.x;
    bars[t] = 0u;                      // 1024 slots (>= NGRP*32)
    if (t == 0) {
        uint32_t acc = 0;
        for (int i = 64; i < 128; ++i) acc |= emb_raw[i];
        *flag = (acc == 0u) ? 0 : 1;
    }
}

// ---------------------------------------------------------------------------
// G[c][j]: input-side gate pre-activations per class. j = q*512 + col,
// q in {0:f, 1:i, 2:o, 3:ctilde}; ctilde quarter pre-sigmoided.
// ---------------------------------------------------------------------------
template <bool BF>
__global__ void build_G(const int* __restrict__ flag,
                        const void* __restrict__ emb,
                        const void* __restrict__ Wfx, const void* __restrict__ Wix,
                        const void* __restrict__ Wox, const void* __restrict__ Wcx,
                        const void* __restrict__ bfv, const void* __restrict__ biv,
                        const void* __restrict__ bov, const void* __restrict__ bcv,
                        float* __restrict__ G) {
    if (*flag != (BF ? 1 : 0)) return;
    const int c   = blockIdx.x;
    const int j   = blockIdx.y * 256 + threadIdx.x;
    const int q   = j >> 9;
    const int col = j & 511;
    const void* W  = (q == 0) ? Wfx : (q == 1) ? Wix : (q == 2) ? Wox : Wcx;
    const void* bv = (q == 0) ? bfv : (q == 1) ? biv : (q == 2) ? bov : bcv;
    float acc = ldv<BF>(bv, col);
    for (int i = 0; i < ID; ++i)
        acc += ldv<BF>(emb, c * ID + i) * ldv<BF>(W, i * HD + col);
    if (q == 3) acc = sigf(acc);
    G[c * 2048 + j] = acc;
}

// ---------------------------------------------------------------------------
// Group-local barrier, fence-free (sc1 data path + relaxed agent atomics).
// The leading __syncthreads drains each wave's sc1 C stores (vmcnt(0))
// before the leader's arrive. Proven in rounds 6-11.
// ---------------------------------------------------------------------------
__device__ __forceinline__ void gbarrier(unsigned int* cnt, unsigned int* iter) {
    __syncthreads();
    if (threadIdx.x == 0) {
        __hip_atomic_fetch_add(cnt, 1u, __ATOMIC_RELAXED, __HIP_MEMORY_SCOPE_AGENT);
        const unsigned int tgt = (*iter + 1u) * GWG;
        while (__hip_atomic_load(cnt, __ATOMIC_RELAXED, __HIP_MEMORY_SCOPE_AGENT) < tgt)
            __builtin_amdgcn_s_sleep(1);
    }
    ++*iter;
    __syncthreads();
}

// ---------------------------------------------------------------------------
// Batch-split recurrence, 16 groups x 16 WGs x 32 cols. Thread t:
//   col = t&31 (own column h0+col), chunk = t>>5 (32 chunks x 16 h'),
//   BOTH gates per thread: wreg = 16 f + 16 i = 32 pinned regs (r11-proven
//   size, no spill). vs r11 this doubles FMAs per LDS C read (8 instead of
//   4): the dot's ds_read_b128 count halves 1024 -> 512 per WG per step —
//   r11's dominant pipe (broadcast return path) per the VALU/wall gap.
// Within a wave the 2 chunk values give 2 distinct LDS addresses -> 2-way
// broadcast, measured free (m136).
// Per step: stage C(t) for 8 rows into LDS (4 sc1 loads/thread) -> dot
// (32 b128 reads, 256 FMA/thread) -> stride-17 partials -> 256 update
// threads sum 32 chunks/gate, apply gates (own C in Creg), sc1-store ->
// group barrier. o-gate once at the end (h dead mid-sequence).
// ---------------------------------------------------------------------------
template <bool BF>
__global__ __launch_bounds__(THR, 1) void recur_bs(
    const int* __restrict__ flag, const int* __restrict__ x,
    const float* __restrict__ G,
    const void* __restrict__ Wfc, const void* __restrict__ Wic,
    const void* __restrict__ Woc,
    float* __restrict__ C0, float* __restrict__ C1,
    float* __restrict__ Hfb, unsigned int* __restrict__ bars)
{
    if (*flag != (BF ? 1 : 0)) return;

    __shared__ __align__(16) float Cs[RPG * CPAD];   // 16.6 KB
    __shared__ float part[THR * PST];                // 69.6 KB, stride 17
    __shared__ int   idx[RPG * TT];                  // 16 KB
    __shared__ int   lz[RPG];

    const int blk   = blockIdx.x;
    const int grp   = blk >> 4;           // 0..15
    const int rank  = blk & 15;           // 0..15
    const int r0    = grp * RPG;
    const int h0    = rank * COLS;
    const int tid   = threadIdx.x;
    const int col   = tid & 31;
    const int chunk = tid >> 5;           // 0..31 (16 h' each)
    unsigned int* bar = bars + grp * 32;  // 128 B apart

    // ---- stage x rows (4096 ints, flat-contiguous), find group start ----
    #pragma unroll
    for (int k = 0; k < 4; ++k)
        idx[tid + 1024 * k] = x[r0 * TT + tid + 1024 * k];
    if (tid < RPG) lz[tid] = -1;
    __syncthreads();
    if (tid < TT)
        #pragma unroll
        for (int r = 0; r < RPG; ++r)
            if (idx[r * TT + tid] == 0) atomicMax(&lz[r], tid);
    __syncthreads();
    int t0 = TT;
    #pragma unroll
    for (int r = 0; r < RPG; ++r) t0 = min(t0, lz[r] + 1);

    // ---- 32 pinned register weights: BOTH gates, own col, own 16-h' chunk
    float wf[16], wi[16];
    {
        #pragma unroll
        for (int k = 0; k < 16; ++k) {
            wf[k] = ldv<BF>(Wfc, (chunk * 16 + k) * HD + h0 + col);
            wi[k] = ldv<BF>(Wic, (chunk * 16 + k) * HD + h0 + col);
        }
        #pragma unroll
        for (int k = 0; k < 16; ++k)
            asm volatile("" : "+v"(wf[k]), "+v"(wi[k]));
    }

    // ---- zero own C slices in both buffers (coherent stores) ----
    if (tid < COLS * RPG) {
        const int c = tid & 31, r = tid >> 5;
        cst(&C0[(r0 + r) * HD + h0 + c], 0.0f);
        cst(&C1[(r0 + r) * HD + h0 + c], 0.0f);
    }
    unsigned int bi = 0;
    gbarrier(bar, &bi);                   // zeros visible group-wide

    float Creg = 0.0f;                    // update threads' own C element
    const int erow = tid >> 7;            // stage: row 0..7
    const int eh4  = (tid & 127) * 4;     // stage: h' base (4 consecutive)

    for (int t = t0; t < TT; ++t) {
        const float* cur = (t & 1) ? C1 : C0;
        float*       nxt = (t & 1) ? C0 : C1;

        // ---- stage C(t): 4 consecutive floats of row erow at h'=eh4 ----
        {
            const float* cb = cur + (r0 + erow) * HD + eh4;
            const float v0 = cld(cb);
            const float v1 = cld(cb + 1);
            const float v2 = cld(cb + 2);
            const float v3 = cld(cb + 3);
            float* cs = Cs + erow * CPAD + eh4;
            cs[0] = v0; cs[1] = v1; cs[2] = v2; cs[3] = v3;
        }
        __syncthreads();

        // ---- both-gate dot over 16 h' (2-way broadcast LDS reads) ----
        float accf[RPG], acci[RPG];
        #pragma unroll
        for (int r = 0; r < RPG; ++r) { accf[r] = 0.0f; acci[r] = 0.0f; }
        {
            const int cb4 = chunk * 4;    // float4 index of chunk base
            #pragma unroll
            for (int j = 0; j < 4; ++j) {
                const float f0 = wf[4*j], f1 = wf[4*j+1], f2 = wf[4*j+2], f3 = wf[4*j+3];
                const float i0 = wi[4*j], i1 = wi[4*j+1], i2 = wi[4*j+2], i3 = wi[4*j+3];
                #pragma unroll
                for (int r = 0; r < RPG; ++r) {
                    const float4 cv = reinterpret_cast<const float4*>(
                        Cs + r * CPAD)[cb4 + j];
                    accf[r] += f0*cv.x + f1*cv.y + f2*cv.z + f3*cv.w;
                    acci[r] += i0*cv.x + i1*cv.y + i2*cv.z + i3*cv.w;
                }
            }
        }
        {
            float* pp = part + tid * PST;
            #pragma unroll
            for (int r = 0; r < RPG; ++r) { pp[r] = accf[r]; pp[8 + r] = acci[r]; }
        }
        __syncthreads();

        // ---- update: thread t<256 owns (col = t&31, row = t>>5) ----
        if (tid < COLS * RPG) {
            const int c = tid & 31, r = tid >> 5;
            float df = 0.f, di = 0.f;
            #pragma unroll
            for (int ch = 0; ch < 32; ++ch) {
                const float* pp = part + (ch * 32 + c) * PST;
                df += pp[r];
                di += pp[8 + r];
            }
            const int cl = idx[r * TT + t];
            const float* Gr = G + cl * 2048;
            float Cn = Gr[1536 + h0 + c] * sigf(Gr[512 + h0 + c] + di)
                     + Creg * sigf(Gr[h0 + c] + df);
            Cn = (cl > 0) ? Cn : 0.0f;
            Creg = Cn;
            cst(&nxt[(r0 + r) * HD + h0 + c], Cn);
        }
        gbarrier(bar, &bi);
    }

    // ---- o-gate + h once (h is dead mid-sequence; TT even -> final C in C0)
    {
        const float* cb = C0 + (r0 + erow) * HD + eh4;
        const float v0 = cld(cb);
        const float v1 = cld(cb + 1);
        const float v2 = cld(cb + 2);
        const float v3 = cld(cb + 3);
        float* cs = Cs + erow * CPAD + eh4;
        cs[0] = v0; cs[1] = v1; cs[2] = v2; cs[3] = v3;
        __syncthreads();

        // thread = (col, chunk of 16 h') for the o-gate dot
        float ao[RPG];
        #pragma unroll
        for (int r = 0; r < RPG; ++r) ao[r] = 0.0f;
        #pragma unroll 4
        for (int k = 0; k < 16; ++k) {
            const int hp = chunk * 16 + k;
            const float wo = ldv<BF>(Woc, hp * HD + h0 + col);
            #pragma unroll
            for (int r = 0; r < RPG; ++r)
                ao[r] += wo * Cs[r * CPAD + hp];
        }
        float* pp = part + tid * PST;
        #pragma unroll
        for (int r = 0; r < RPG; ++r) pp[r] = ao[r];
        __syncthreads();
        if (tid < COLS * RPG) {
            const int c = tid & 31, r = tid >> 5;
            float s = 0.f;
            #pragma unroll
            for (int ch = 0; ch < 32; ++ch)
                s += part[(ch * 32 + c) * PST + r];
            const int cl = idx[r * TT + TT - 1];
            const float o = sigf(G[cl * 2048 + 1024 + h0 + c] + s);
            Hfb[(r0 + r) * HD + h0 + c] = tanhf(Creg) * o;
        }
    }
}

// ---------------------------------------------------------------------------
// Projection + log_softmax, one WG per batch row.
// ---------------------------------------------------------------------------
template <bool BF>
__global__ __launch_bounds__(128) void proj(
    const int* __restrict__ flag, const float* __restrict__ Hfb,
    const void* __restrict__ Wph, const void* __restrict__ bp,
    void* __restrict__ out)
{
    if (*flag != (BF ? 1 : 0)) return;
    __shared__ __align__(16) float hv[HD];
    __shared__ float p_s[NCLS];
    __shared__ float lse_s;
    const int b   = blockIdx.x;
    const int tid = threadIdx.x;

    reinterpret_cast<float4*>(hv)[tid] =
        reinterpret_cast<const float4*>(Hfb + b * HD)[tid];
    __syncthreads();

    if (tid < NCLS) {
        float p = ldv<BF>(bp, tid);
        for (int h = 0; h < HD; ++h)
            p += hv[h] * ldv<BF>(Wph, h * NCLS + tid);
        p_s[tid] = p;
    }
    __syncthreads();
    if (tid == 0) {
        float m = -1e30f;
        for (int n = 0; n < NCLS; ++n) m = fmaxf(m, p_s[n]);
        float sum = 0.0f;
        for (int n = 0; n < NCLS; ++n) sum += expf(p_s[n] - m);
        lse_s = m + logf(sum);
    }
    __syncthreads();
    if (tid < NCLS) {
        const float v = p_s[tid] - lse_s;
        if constexpr (BF) ((bf16*)out)[b * NCLS + tid] = __float2bfloat16(v);
        else              ((float*)out)[b * NCLS + tid] = v;
    }
}

// ---------------------------------------------------------------------------
extern "C" void kernel_launch(void* const* d_in, const int* in_sizes, int n_in,
                              void* d_out, int out_size, void* d_ws, size_t ws_size,
                              hipStream_t stream) {
    const int*  x   = (const int*)d_in[0];
    const void* emb = d_in[1];
    const void* Wfx = d_in[2];
    const void* Wfc = d_in[3];
    const void* bfv = d_in[4];
    const void* Wix = d_in[5];
    const void* Wic = d_in[6];
    const void* biv = d_in[7];
    const void* Wox = d_in[8];
    const void* Woc = d_in[9];
    const void* bov = d_in[10];
    const void* Wcx = d_in[11];
    const void* bcv = d_in[12];
    const void* Wph = d_in[13];
    const void* bp  = d_in[14];

    int*          flag = (int*)((char*)d_ws + WS_FLAG);
    unsigned int* bars = (unsigned int*)((char*)d_ws + WS_BAR);
    float*        G    = (float*)((char*)d_ws + WS_G);
    float*        C0   = (float*)((char*)d_ws + WS_C0);
    float*        C1   = (float*)((char*)d_ws + WS_C1);
    float*        Hfb  = (float*)((char*)d_ws + WS_HFB);

    init_k<<<1, 1024, 0, stream>>>((const uint32_t*)emb, flag, bars);

    build_G<false><<<dim3(NEMB, 8), 256, 0, stream>>>(flag, emb, Wfx, Wix, Wox, Wcx,
                                                      bfv, biv, bov, bcv, G);
    build_G<true ><<<dim3(NEMB, 8), 256, 0, stream>>>(flag, emb, Wfx, Wix, Wox, Wcx,
                                                      bfv, biv, bov, bcv, G);

    {
        void* args[] = {(void*)&flag, (void*)&x, (void*)&G,
                        (void*)&Wfc, (void*)&Wic, (void*)&Woc,
                        (void*)&C0, (void*)&C1, (void*)&Hfb, (void*)&bars};
        hipLaunchCooperativeKernel((const void*)recur_bs<false>, dim3(NGRP * GWG), dim3(THR),
                                   args, 0, stream);
        hipLaunchCooperativeKernel((const void*)recur_bs<true>, dim3(NGRP * GWG), dim3(THR),
                                   args, 0, stream);
    }

    proj<false><<<BB, 128, 0, stream>>>(flag, Hfb, Wph, bp, d_out);
    proj<true ><<<BB, 128, 0, stream>>>(flag, Hfb, Wph, bp, d_out);
}

// Round 13
// 2256.406 us; speedup vs baseline: 2.2927x; 1.0113x over previous
//
#include <hip/hip_runtime.h>
#include <hip/hip_bf16.h>
#include <stdint.h>

#define HD   512   // hidden dim H
#define ID   128   // input dim I
#define NCLS 100   // num classes
#define TT   512   // sequence length T
#define BB   128   // batch B
#define NEMB 101   // NC + 1 embedding rows
#define NGRP 16    // independent batch groups
#define GWG  16    // workgroups per group (sync clique)
#define RPG  8     // batch rows per group
#define COLS 32    // hidden cols per WG (GWG*COLS == HD)
#define THR  1024  // threads per recurrence WG (16 waves, 4 waves/SIMD)
#define CPAD 520   // LDS C row stride (mult of 4 -> float4-aligned; skews banks)
#define PST2 9     // partials stride in float2 units (odd -> bank-skewed)

// workspace layout (bytes)
#define WS_FLAG 0
#define WS_BAR  1024                  // uint bars[NGRP*32] (128 B apart)
#define WS_G    16384                 // float G[101][2048]  (808 KB)
#define WS_C0   (1u * 1024 * 1024)    // float C0[128][512]  (256 KB)
#define WS_C1   (WS_C0 + 262144)      // float C1[128][512]  (256 KB)
#define WS_HFB  (WS_C1 + 262144)      // float Hfb[128][512] (256 KB)

using bf16 = __hip_bfloat16;

__device__ __forceinline__ float b2f(bf16 v) { return __bfloat162float(v); }
__device__ __forceinline__ float sigf(float x) { return 1.0f / (1.0f + expf(-x)); }

// coherent (IF-scope) C-state accessors: sc1 loads/stores bypass the
// non-coherent per-XCD L2 — no fences / cache-maintenance needed (proven r6-r12).
__device__ __forceinline__ float cld(const float* p) {
    return __hip_atomic_load(p, __ATOMIC_RELAXED, __HIP_MEMORY_SCOPE_AGENT);
}
__device__ __forceinline__ void cst(float* p, float v) {
    __hip_atomic_store(p, v, __ATOMIC_RELAXED, __HIP_MEMORY_SCOPE_AGENT);
}

template <bool BF>
__device__ __forceinline__ float ldv(const void* p, int i) {
    if constexpr (BF) return b2f(((const bf16*)p)[i]);
    else              return ((const float*)p)[i];
}

// ---------------------------------------------------------------------------
// Dtype sniffer + barrier zeroing. emb row 0 is exactly 0.0 by construction:
// bytes [256,512) are zero iff f32 (row 0) and nonzero iff bf16 (row 1).
// ---------------------------------------------------------------------------
__global__ void init_k(const uint32_t* __restrict__ emb_raw,
                       int* __restrict__ flag, unsigned int* __restrict__ bars) {
    const int t = threadIdx.x;
    bars[t] = 0u;                      // 1024 slots (>= NGRP*32)
    if (t == 0) {
        uint32_t acc = 0;
        for (int i = 64; i < 128; ++i) acc |= emb_raw[i];
        *flag = (acc == 0u) ? 0 : 1;
    }
}

// ---------------------------------------------------------------------------
// G[c][j]: input-side gate pre-activations per class. j = q*512 + col,
// q in {0:f, 1:i, 2:o, 3:ctilde}; ctilde quarter pre-sigmoided.
// ---------------------------------------------------------------------------
template <bool BF>
__global__ void build_G(const int* __restrict__ flag,
                        const void* __restrict__ emb,
                        const void* __restrict__ Wfx, const void* __restrict__ Wix,
                        const void* __restrict__ Wox, const void* __restrict__ Wcx,
                        const void* __restrict__ bfv, const void* __restrict__ biv,
                        const void* __restrict__ bov, const void* __restrict__ bcv,
                        float* __restrict__ G) {
    if (*flag != (BF ? 1 : 0)) return;
    const int c   = blockIdx.x;
    const int j   = blockIdx.y * 256 + threadIdx.x;
    const int q   = j >> 9;
    const int col = j & 511;
    const void* W  = (q == 0) ? Wfx : (q == 1) ? Wix : (q == 2) ? Wox : Wcx;
    const void* bv = (q == 0) ? bfv : (q == 1) ? biv : (q == 2) ? bov : bcv;
    float acc = ldv<BF>(bv, col);
    for (int i = 0; i < ID; ++i)
        acc += ldv<BF>(emb, c * ID + i) * ldv<BF>(W, i * HD + col);
    if (q == 3) acc = sigf(acc);
    G[c * 2048 + j] = acc;
}

// ---------------------------------------------------------------------------
// Group-local barrier, fence-free (sc1 data path + relaxed agent atomics).
// The leading __syncthreads drains each wave's sc1 C stores (vmcnt(0))
// before the leader's arrive. Tight poll (no s_sleep): 1 WG/CU, the spin
// starves nothing and shaves the sleep quantum off the release latency.
// ---------------------------------------------------------------------------
__device__ __forceinline__ void gbarrier(unsigned int* cnt, unsigned int* iter) {
    __syncthreads();
    if (threadIdx.x == 0) {
        __hip_atomic_fetch_add(cnt, 1u, __ATOMIC_RELAXED, __HIP_MEMORY_SCOPE_AGENT);
        const unsigned int tgt = (*iter + 1u) * GWG;
        while (__hip_atomic_load(cnt, __ATOMIC_RELAXED, __HIP_MEMORY_SCOPE_AGENT) < tgt)
            ;
    }
    ++*iter;
    __syncthreads();
}

// ---------------------------------------------------------------------------
// Batch-split recurrence, 16 groups x 16 WGs x 32 cols. Thread t:
//   col = t&31, chunk = t>>5 (32 chunks x 16 h'), BOTH gates per thread:
//   32 pinned regs (r11/r12-proven size, no spill).
// r13 deltas vs r12:
//   - partials packed as float2 (f,i): dot writes 8 b64 (was 16 b32),
//     update reads 32 b64 (was 64 b32) — the update-phase LDS insts halve.
//   - G gate operands prefetched at step top (overlap the dot's latency).
//   - tight barrier poll.
// Per step: [prefetch G] stage C(t) (4 sc1 loads/thread) -> sync -> dot
// (32 b128 broadcast reads, 256 FMA/thread) -> float2 partials -> sync ->
// 256 update threads (32 b64 reads, gates, own C in Creg, sc1-store) ->
// group barrier. o-gate once at the end (h dead mid-sequence).
// ---------------------------------------------------------------------------
template <bool BF>
__global__ __launch_bounds__(THR, 1) void recur_bs(
    const int* __restrict__ flag, const int* __restrict__ x,
    const float* __restrict__ G,
    const void* __restrict__ Wfc, const void* __restrict__ Wic,
    const void* __restrict__ Woc,
    float* __restrict__ C0, float* __restrict__ C1,
    float* __restrict__ Hfb, unsigned int* __restrict__ bars)
{
    if (*flag != (BF ? 1 : 0)) return;

    __shared__ __align__(16) float Cs[RPG * CPAD];   // 16.6 KB
    __shared__ __align__(8)  float2 part2[THR * PST2]; // 73.7 KB
    __shared__ int   idx[RPG * TT];                  // 16 KB
    __shared__ int   lz[RPG];

    const int blk   = blockIdx.x;
    const int grp   = blk >> 4;           // 0..15
    const int rank  = blk & 15;           // 0..15
    const int r0    = grp * RPG;
    const int h0    = rank * COLS;
    const int tid   = threadIdx.x;
    const int col   = tid & 31;
    const int chunk = tid >> 5;           // 0..31 (16 h' each)
    unsigned int* bar = bars + grp * 32;  // 128 B apart

    // ---- stage x rows (4096 ints, flat-contiguous), find group start ----
    #pragma unroll
    for (int k = 0; k < 4; ++k)
        idx[tid + 1024 * k] = x[r0 * TT + tid + 1024 * k];
    if (tid < RPG) lz[tid] = -1;
    __syncthreads();
    if (tid < TT)
        #pragma unroll
        for (int r = 0; r < RPG; ++r)
            if (idx[r * TT + tid] == 0) atomicMax(&lz[r], tid);
    __syncthreads();
    int t0 = TT;
    #pragma unroll
    for (int r = 0; r < RPG; ++r) t0 = min(t0, lz[r] + 1);

    // ---- 32 pinned register weights: BOTH gates, own col, own 16-h' chunk
    float wf[16], wi[16];
    {
        #pragma unroll
        for (int k = 0; k < 16; ++k) {
            wf[k] = ldv<BF>(Wfc, (chunk * 16 + k) * HD + h0 + col);
            wi[k] = ldv<BF>(Wic, (chunk * 16 + k) * HD + h0 + col);
        }
        #pragma unroll
        for (int k = 0; k < 16; ++k)
            asm volatile("" : "+v"(wf[k]), "+v"(wi[k]));
    }

    // ---- zero own C slices in both buffers (coherent stores) ----
    if (tid < COLS * RPG) {
        const int c = tid & 31, r = tid >> 5;
        cst(&C0[(r0 + r) * HD + h0 + c], 0.0f);
        cst(&C1[(r0 + r) * HD + h0 + c], 0.0f);
    }
    unsigned int bi = 0;
    gbarrier(bar, &bi);                   // zeros visible group-wide

    float Creg = 0.0f;                    // update threads' own C element
    const int erow = tid >> 7;            // stage: row 0..7
    const int eh4  = (tid & 127) * 4;     // stage: h' base (4 consecutive)
    const bool isUpd = (tid < COLS * RPG);
    const int uc = tid & 31, ur = tid >> 5;   // update thread's (col, row)

    for (int t = t0; t < TT; ++t) {
        const float* cur = (t & 1) ? C1 : C0;
        float*       nxt = (t & 1) ? C0 : C1;

        // ---- prefetch G gate operands for the update (overlaps the dot) --
        float gf = 0.f, gi = 0.f, sgc = 0.f;
        int cl = 1;
        if (isUpd) {
            cl = idx[ur * TT + t];
            const float* Gr = G + cl * 2048;
            gf  = Gr[h0 + uc];
            gi  = Gr[512 + h0 + uc];
            sgc = Gr[1536 + h0 + uc];
        }

        // ---- stage C(t): 4 consecutive floats of row erow at h'=eh4 ----
        {
            const float* cb = cur + (r0 + erow) * HD + eh4;
            const float v0 = cld(cb);
            const float v1 = cld(cb + 1);
            const float v2 = cld(cb + 2);
            const float v3 = cld(cb + 3);
            float* cs = Cs + erow * CPAD + eh4;
            cs[0] = v0; cs[1] = v1; cs[2] = v2; cs[3] = v3;
        }
        __syncthreads();

        // ---- both-gate dot over 16 h' (2-way broadcast LDS reads) ----
        float accf[RPG], acci[RPG];
        #pragma unroll
        for (int r = 0; r < RPG; ++r) { accf[r] = 0.0f; acci[r] = 0.0f; }
        {
            const int cb4 = chunk * 4;    // float4 index of chunk base
            #pragma unroll
            for (int j = 0; j < 4; ++j) {
                const float f0 = wf[4*j], f1 = wf[4*j+1], f2 = wf[4*j+2], f3 = wf[4*j+3];
                const float i0 = wi[4*j], i1 = wi[4*j+1], i2 = wi[4*j+2], i3 = wi[4*j+3];
                #pragma unroll
                for (int r = 0; r < RPG; ++r) {
                    const float4 cv = reinterpret_cast<const float4*>(
                        Cs + r * CPAD)[cb4 + j];
                    accf[r] += f0*cv.x + f1*cv.y + f2*cv.z + f3*cv.w;
                    acci[r] += i0*cv.x + i1*cv.y + i2*cv.z + i3*cv.w;
                }
            }
        }
        {
            float2* pp = part2 + tid * PST2;
            #pragma unroll
            for (int r = 0; r < RPG; ++r)
                pp[r] = make_float2(accf[r], acci[r]);
        }
        __syncthreads();

        // ---- update: thread t<256 owns (col = uc, row = ur) ----
        if (isUpd) {
            float df = 0.f, di = 0.f;
            #pragma unroll
            for (int ch = 0; ch < 32; ++ch) {
                const float2 v = part2[(ch * 32 + uc) * PST2 + ur];
                df += v.x;
                di += v.y;
            }
            float Cn = sgc * sigf(gi + di) + Creg * sigf(gf + df);
            Cn = (cl > 0) ? Cn : 0.0f;
            Creg = Cn;
            cst(&nxt[(r0 + ur) * HD + h0 + uc], Cn);
        }
        gbarrier(bar, &bi);
    }

    // ---- o-gate + h once (h is dead mid-sequence; TT even -> final C in C0)
    {
        const float* cb = C0 + (r0 + erow) * HD + eh4;
        const float v0 = cld(cb);
        const float v1 = cld(cb + 1);
        const float v2 = cld(cb + 2);
        const float v3 = cld(cb + 3);
        float* cs = Cs + erow * CPAD + eh4;
        cs[0] = v0; cs[1] = v1; cs[2] = v2; cs[3] = v3;
        __syncthreads();

        // thread = (col, chunk of 16 h') for the o-gate dot
        float ao[RPG];
        #pragma unroll
        for (int r = 0; r < RPG; ++r) ao[r] = 0.0f;
        #pragma unroll 4
        for (int k = 0; k < 16; ++k) {
            const int hp = chunk * 16 + k;
            const float wo = ldv<BF>(Woc, hp * HD + h0 + col);
            #pragma unroll
            for (int r = 0; r < RPG; ++r)
                ao[r] += wo * Cs[r * CPAD + hp];
        }
        {
            float2* pp = part2 + tid * PST2;
            #pragma unroll
            for (int r2 = 0; r2 < RPG / 2; ++r2)
                pp[r2] = make_float2(ao[2 * r2], ao[2 * r2 + 1]);
        }
        __syncthreads();
        if (isUpd) {
            float s = 0.f;
            #pragma unroll
            for (int ch = 0; ch < 32; ++ch) {
                const float2 v = part2[(ch * 32 + uc) * PST2 + (ur >> 1)];
                s += (ur & 1) ? v.y : v.x;
            }
            const int cl2 = idx[ur * TT + TT - 1];
            const float o = sigf(G[cl2 * 2048 + 1024 + h0 + uc] + s);
            Hfb[(r0 + ur) * HD + h0 + uc] = tanhf(Creg) * o;
        }
    }
}

// ---------------------------------------------------------------------------
// Projection + log_softmax, one WG per batch row.
// ---------------------------------------------------------------------------
template <bool BF>
__global__ __launch_bounds__(128) void proj(
    const int* __restrict__ flag, const float* __restrict__ Hfb,
    const void* __restrict__ Wph, const void* __restrict__ bp,
    void* __restrict__ out)
{
    if (*flag != (BF ? 1 : 0)) return;
    __shared__ __align__(16) float hv[HD];
    __shared__ float p_s[NCLS];
    __shared__ float lse_s;
    const int b   = blockIdx.x;
    const int tid = threadIdx.x;

    reinterpret_cast<float4*>(hv)[tid] =
        reinterpret_cast<const float4*>(Hfb + b * HD)[tid];
    __syncthreads();

    if (tid < NCLS) {
        float p = ldv<BF>(bp, tid);
        for (int h = 0; h < HD; ++h)
            p += hv[h] * ldv<BF>(Wph, h * NCLS + tid);
        p_s[tid] = p;
    }
    __syncthreads();
    if (tid == 0) {
        float m = -1e30f;
        for (int n = 0; n < NCLS; ++n) m = fmaxf(m, p_s[n]);
        float sum = 0.0f;
        for (int n = 0; n < NCLS; ++n) sum += expf(p_s[n] - m);
        lse_s = m + logf(sum);
    }
    __syncthreads();
    if (tid < NCLS) {
        const float v = p_s[tid] - lse_s;
        if constexpr (BF) ((bf16*)out)[b * NCLS + tid] = __float2bfloat16(v);
        else              ((float*)out)[b * NCLS + tid] = v;
    }
}

// ---------------------------------------------------------------------------
extern "C" void kernel_launch(void* const* d_in, const int* in_sizes, int n_in,
                              void* d_out, int out_size, void* d_ws, size_t ws_size,
                              hipStream_t stream) {
    const int*  x   = (const int*)d_in[0];
    const void* emb = d_in[1];
    const void* Wfx = d_in[2];
    const void* Wfc = d_in[3];
    const void* bfv = d_in[4];
    const void* Wix = d_in[5];
    const void* Wic = d_in[6];
    const void* biv = d_in[7];
    const void* Wox = d_in[8];
    const void* Woc = d_in[9];
    const void* bov = d_in[10];
    const void* Wcx = d_in[11];
    const void* bcv = d_in[12];
    const void* Wph = d_in[13];
    const void* bp  = d_in[14];

    int*          flag = (int*)((char*)d_ws + WS_FLAG);
    unsigned int* bars = (unsigned int*)((char*)d_ws + WS_BAR);
    float*        G    = (float*)((char*)d_ws + WS_G);
    float*        C0   = (float*)((char*)d_ws + WS_C0);
    float*        C1   = (float*)((char*)d_ws + WS_C1);
    float*        Hfb  = (float*)((char*)d_ws + WS_HFB);

    init_k<<<1, 1024, 0, stream>>>((const uint32_t*)emb, flag, bars);

    build_G<false><<<dim3(NEMB, 8), 256, 0, stream>>>(flag, emb, Wfx, Wix, Wox, Wcx,
                                                      bfv, biv, bov, bcv, G);
    build_G<true ><<<dim3(NEMB, 8), 256, 0, stream>>>(flag, emb, Wfx, Wix, Wox, Wcx,
                                                      bfv, biv, bov, bcv, G);

    {
        void* args[] = {(void*)&flag, (void*)&x, (void*)&G,
                        (void*)&Wfc, (void*)&Wic, (void*)&Woc,
                        (void*)&C0, (void*)&C1, (void*)&Hfb, (void*)&bars};
        hipLaunchCooperativeKernel((const void*)recur_bs<false>, dim3(NGRP * GWG), dim3(THR),
                                   args, 0, stream);
        hipLaunchCooperativeKernel((const void*)recur_bs<true>, dim3(NGRP * GWG), dim3(THR),
                                   args, 0, stream);
    }

    proj<false><<<BB, 128, 0, stream>>>(flag, Hfb, Wph, bp, d_out);
    proj<true ><<<BB, 128, 0, stream>>>(flag, Hfb, Wph, bp, d_out);
}